// Round 11
// baseline (276.739 us; speedup 1.0000x reference)
//
#include <hip/hip_runtime.h>

#define D 128
#define DH 64  // D/2 (float2 pairs)
#define KC 32  // GEMM k-chunk

// ---------------------------------------------------------------------------
// CSR build: count -> multiblock scan (A/B/C) -> fill (all bounds-checked)
// count/fill: int4-vectorized (4 edges/thread), scalar tail in-kernel.
// ---------------------------------------------------------------------------
__global__ __launch_bounds__(256) void count_kernel_vec(
    const int* __restrict__ dst, int* __restrict__ cnt, int E, int N)
{
    int t = blockIdx.x * 256 + threadIdx.x;
    int E4 = E >> 2;
    if (t < E4) {
        int4 d = ((const int4*)dst)[t];
        if ((unsigned)d.x < (unsigned)N) atomicAdd(&cnt[d.x], 1);
        if ((unsigned)d.y < (unsigned)N) atomicAdd(&cnt[d.y], 1);
        if ((unsigned)d.z < (unsigned)N) atomicAdd(&cnt[d.z], 1);
        if ((unsigned)d.w < (unsigned)N) atomicAdd(&cnt[d.w], 1);
    } else if (t == E4) {
        for (int e = E4 * 4; e < E; ++e) {
            int d = dst[e];
            if ((unsigned)d < (unsigned)N) atomicAdd(&cnt[d], 1);
        }
    }
}

__global__ __launch_bounds__(256) void count_kernel(
    const int* __restrict__ dst, int* __restrict__ cnt, int E, int N)
{
    int e = blockIdx.x * 256 + threadIdx.x;
    if (e >= E) return;
    int d = dst[e];
    if ((unsigned)d < (unsigned)N) atomicAdd(&cnt[d], 1);
}

__global__ __launch_bounds__(256) void blocksum_kernel(
    const int* __restrict__ cnt, int* __restrict__ bsum, int N)
{
    __shared__ int lds[256];
    const int base = blockIdx.x * 1024;
    const int t = threadIdx.x;
    int s = 0;
    #pragma unroll
    for (int p = 0; p < 4; ++p) {
        int k = base + p * 256 + t;
        if (k < N) s += cnt[k];
    }
    lds[t] = s;
    __syncthreads();
    for (int off = 128; off > 0; off >>= 1) {
        if (t < off) lds[t] += lds[t + off];
        __syncthreads();
    }
    if (t == 0) bsum[blockIdx.x] = lds[0];
}

__global__ __launch_bounds__(256) void scanbsum_kernel(
    int* __restrict__ bsum, int* __restrict__ rowptrN, int NB)
{
    __shared__ int lds[256];
    const int t = threadIdx.x;
    int v = (t < NB) ? bsum[t] : 0;
    lds[t] = v;
    __syncthreads();
    for (int off = 1; off < 256; off <<= 1) {
        int u = (t >= off) ? lds[t - off] : 0;
        __syncthreads();
        lds[t] += u;
        __syncthreads();
    }
    if (t < NB) bsum[t] = lds[t] - v;   // exclusive block offset
    if (t == 255) *rowptrN = lds[255];  // grand total
}

__global__ __launch_bounds__(256) void scanwrite_kernel(
    const int* __restrict__ cnt, const int* __restrict__ bsum,
    int* __restrict__ rowptr, int* __restrict__ cursor, int N)
{
    __shared__ int lds[256];
    const int base = blockIdx.x * 1024;
    const int t = threadIdx.x;
    int offset = bsum[blockIdx.x];
    #pragma unroll
    for (int p = 0; p < 4; ++p) {
        int k = base + p * 256 + t;
        int v = (k < N) ? cnt[k] : 0;
        lds[t] = v;
        __syncthreads();
        for (int off = 1; off < 256; off <<= 1) {
            int u = (t >= off) ? lds[t - off] : 0;
            __syncthreads();
            lds[t] += u;
            __syncthreads();
        }
        int excl = offset + lds[t] - v;
        if (k < N) { rowptr[k] = excl; cursor[k] = excl; }
        offset += lds[255];
        __syncthreads();
    }
}

__global__ __launch_bounds__(256) void fill_kernel_vec(
    const int* __restrict__ src, const int* __restrict__ dst,
    int* __restrict__ cursor, int* __restrict__ esrc, int E, int N)
{
    int t = blockIdx.x * 256 + threadIdx.x;
    int E4 = E >> 2;
    if (t < E4) {
        int4 s = ((const int4*)src)[t];
        int4 d = ((const int4*)dst)[t];
        if ((unsigned)d.x < (unsigned)N) { int p = atomicAdd(&cursor[d.x], 1); if ((unsigned)p < (unsigned)E) esrc[p] = s.x; }
        if ((unsigned)d.y < (unsigned)N) { int p = atomicAdd(&cursor[d.y], 1); if ((unsigned)p < (unsigned)E) esrc[p] = s.y; }
        if ((unsigned)d.z < (unsigned)N) { int p = atomicAdd(&cursor[d.z], 1); if ((unsigned)p < (unsigned)E) esrc[p] = s.z; }
        if ((unsigned)d.w < (unsigned)N) { int p = atomicAdd(&cursor[d.w], 1); if ((unsigned)p < (unsigned)E) esrc[p] = s.w; }
    } else if (t == E4) {
        for (int e = E4 * 4; e < E; ++e) {
            int d = dst[e];
            if ((unsigned)d < (unsigned)N) {
                int p = atomicAdd(&cursor[d], 1);
                if ((unsigned)p < (unsigned)E) esrc[p] = src[e];
            }
        }
    }
}

__global__ __launch_bounds__(256) void fill_kernel(
    const int* __restrict__ src, const int* __restrict__ dst,
    int* __restrict__ cursor, int* __restrict__ esrc, int E, int N)
{
    int e = blockIdx.x * 256 + threadIdx.x;
    if (e >= E) return;
    int d = dst[e];
    if ((unsigned)d >= (unsigned)N) return;
    int p = atomicAdd(&cursor[d], 1);
    if ((unsigned)p < (unsigned)E) esrc[p] = src[e];
}

// ---------------------------------------------------------------------------
// Gather: half-wave (32 lanes, float4) per node -> 2 nodes per wave.
// h[i] = (1+eps)*x[i] + sum_{j in nbr(i)} x[j]; unrolled x8 for ILP
// (8 independent 512B row-loads in flight per half-wave).
// h written fp32 into d_out (overwritten later by hlin then out, in order).
// ---------------------------------------------------------------------------
__global__ __launch_bounds__(256) void gather_kernel(
    const float4* __restrict__ x4, const int* __restrict__ rowptr,
    const int* __restrict__ esrc, const float* __restrict__ geps,
    float4* __restrict__ h4, int N, int E)
{
    const float eps1 = 1.0f + geps[0];
    const int node = blockIdx.x * 8 + (threadIdx.x >> 5);
    const int lane = threadIdx.x & 31;       // 32 float4 slots per row
    if (node >= N) return;
    int s0 = rowptr[node];
    int s1 = rowptr[node + 1];
    s0 = max(0, min(s0, E));       // any CSR bug stays finite
    s1 = max(s0, min(s1, E));
    float4 a = x4[(long)node * 32 + lane];
    a.x *= eps1; a.y *= eps1; a.z *= eps1; a.w *= eps1;
    const float4 z4 = make_float4(0.f, 0.f, 0.f, 0.f);
    int e = s0;
    for (; e + 7 < s1; e += 8) {
        int j[8];
        #pragma unroll
        for (int q = 0; q < 8; ++q) j[q] = esrc[e + q];
        float4 v[8];
        #pragma unroll
        for (int q = 0; q < 8; ++q) {
            v[q] = ((unsigned)j[q] < (unsigned)N) ? x4[(long)j[q] * 32 + lane] : z4;
        }
        float4 s01 = make_float4(v[0].x + v[1].x, v[0].y + v[1].y, v[0].z + v[1].z, v[0].w + v[1].w);
        float4 s23 = make_float4(v[2].x + v[3].x, v[2].y + v[3].y, v[2].z + v[3].z, v[2].w + v[3].w);
        float4 s45 = make_float4(v[4].x + v[5].x, v[4].y + v[5].y, v[4].z + v[5].z, v[4].w + v[5].w);
        float4 s67 = make_float4(v[6].x + v[7].x, v[6].y + v[7].y, v[6].z + v[7].z, v[6].w + v[7].w);
        a.x += (s01.x + s23.x) + (s45.x + s67.x);
        a.y += (s01.y + s23.y) + (s45.y + s67.y);
        a.z += (s01.z + s23.z) + (s45.z + s67.z);
        a.w += (s01.w + s23.w) + (s45.w + s67.w);
    }
    for (; e < s1; ++e) {
        int j = esrc[e];
        if ((unsigned)j < (unsigned)N) {
            float4 v = x4[(long)j * 32 + lane];
            a.x += v.x; a.y += v.y; a.z += v.z; a.w += v.w;
        }
    }
    h4[(long)node * 32 + lane] = a;
}

// ---------------------------------------------------------------------------
// Register-tiled GEMM + BN stats: hlin = h @ W^T + b, col sum/sumsq.
// Block = 256 threads = 16(tx) x 16(ty); tile 64 rows x 128 cols; each thread
// owns c[4][8]. hb read AND written in-place (d_out); rows block-private.
// ---------------------------------------------------------------------------
__global__ __launch_bounds__(256) void gemm_stats_kernel(
    float* hb, const float* __restrict__ W,
    const float* __restrict__ bb, float* __restrict__ stats, int N)
{
    __shared__ __align__(16) float At[KC][68];
    __shared__ __align__(16) float Bs[KC][132];
    __shared__ float red[16][128];

    const int tid = threadIdx.x;
    const int tx = tid & 15;
    const int ty = tid >> 4;
    const int row0 = blockIdx.x * 64;

    float c[4][8];
    #pragma unroll
    for (int r = 0; r < 4; ++r)
        #pragma unroll
        for (int cc = 0; cc < 8; ++cc) c[r][cc] = 0.0f;

    for (int k0 = 0; k0 < D; k0 += KC) {
        #pragma unroll
        for (int q = 0; q < 2; ++q) {
            int s = q * 256 + tid;
            int r = s >> 3;
            int kq = s & 7;
            int grow = row0 + r;
            float4 v = make_float4(0.f, 0.f, 0.f, 0.f);
            if (grow < N) v = *(const float4*)(hb + (long)grow * D + k0 + kq * 4);
            At[kq * 4 + 0][r] = v.x; At[kq * 4 + 1][r] = v.y;
            At[kq * 4 + 2][r] = v.z; At[kq * 4 + 3][r] = v.w;
        }
        #pragma unroll
        for (int q = 0; q < 4; ++q) {
            int s = q * 256 + tid;
            int col = s >> 3;
            int kq = s & 7;
            float4 v = *(const float4*)(W + (long)col * D + k0 + kq * 4);
            Bs[kq * 4 + 0][col] = v.x; Bs[kq * 4 + 1][col] = v.y;
            Bs[kq * 4 + 2][col] = v.z; Bs[kq * 4 + 3][col] = v.w;
        }
        __syncthreads();
        #pragma unroll
        for (int k = 0; k < KC; ++k) {
            float4 av = *(const float4*)&At[k][ty * 4];
            float4 b0 = *(const float4*)&Bs[k][tx * 8];
            float4 b1 = *(const float4*)&Bs[k][tx * 8 + 4];
            float a[4] = {av.x, av.y, av.z, av.w};
            float b[8] = {b0.x, b0.y, b0.z, b0.w, b1.x, b1.y, b1.z, b1.w};
            #pragma unroll
            for (int r = 0; r < 4; ++r)
                #pragma unroll
                for (int cc = 0; cc < 8; ++cc)
                    c[r][cc] = fmaf(a[r], b[cc], c[r][cc]);
        }
        __syncthreads();
    }

    float bias[8];
    #pragma unroll
    for (int cc = 0; cc < 8; ++cc) bias[cc] = bb[tx * 8 + cc];

    float psum[8], psq[8];
    #pragma unroll
    for (int cc = 0; cc < 8; ++cc) { psum[cc] = 0.f; psq[cc] = 0.f; }

    #pragma unroll
    for (int r = 0; r < 4; ++r) {
        int grow = row0 + ty * 4 + r;
        if (grow < N) {
            float v[8];
            #pragma unroll
            for (int cc = 0; cc < 8; ++cc) {
                v[cc] = c[r][cc] + bias[cc];
                psum[cc] += v[cc];
                psq[cc]  = fmaf(v[cc], v[cc], psq[cc]);
            }
            float4* dst0 = (float4*)(hb + (long)grow * D + tx * 8);
            dst0[0] = make_float4(v[0], v[1], v[2], v[3]);
            dst0[1] = make_float4(v[4], v[5], v[6], v[7]);
        }
    }

    #pragma unroll
    for (int cc = 0; cc < 8; ++cc) red[ty][tx * 8 + cc] = psum[cc];
    __syncthreads();
    if (tid < 128) {
        float s = 0.f;
        #pragma unroll
        for (int t = 0; t < 16; ++t) s += red[t][tid];
        unsafeAtomicAdd(&stats[tid], s);
    }
    __syncthreads();
    #pragma unroll
    for (int cc = 0; cc < 8; ++cc) red[ty][tx * 8 + cc] = psq[cc];
    __syncthreads();
    if (tid < 128) {
        float s = 0.f;
        #pragma unroll
        for (int t = 0; t < 16; ++t) s += red[t][tid];
        unsafeAtomicAdd(&stats[128 + tid], s);
    }
}

// ---------------------------------------------------------------------------
// Epilogue (finalize fused): each block derives ginv/shift from raw stats
// (sum/sumsq), then out = relu(hlin*ginv + shift) + x. Same-index float2
// alias (read pair t, write pair t) -> race-free. NO __restrict__ on alias.
// ---------------------------------------------------------------------------
__global__ __launch_bounds__(256) void out_kernel(
    const float2* hlin2, const float2* __restrict__ x2,
    const float* __restrict__ stats, const float* __restrict__ gamma,
    const float* __restrict__ beta, float invN, float2* dout, long total)
{
    __shared__ float ginv[D], sh[D];
    if (threadIdx.x < D) {
        int j = threadIdx.x;
        float mean = stats[j] * invN;
        float var  = stats[128 + j] * invN - mean * mean;
        float gv   = gamma[j] * rsqrtf(var + 1e-5f);
        ginv[j] = gv;
        sh[j]   = beta[j] - mean * gv;
    }
    __syncthreads();
    long t = (long)blockIdx.x * 256 + threadIdx.x;
    if (t >= total) return;
    int f = (int)(t & 63);
    float2 hv = hlin2[t];
    float2 xv = x2[t];
    float v0 = fmaf(hv.x, ginv[2 * f],     sh[2 * f]);
    float v1 = fmaf(hv.y, ginv[2 * f + 1], sh[2 * f + 1]);
    v0 = fmaxf(v0, 0.0f) + xv.x;
    v1 = fmaxf(v1, 0.0f) + xv.y;
    dout[t] = make_float2(v0, v1);
}

// ---------------------------------------------------------------------------
static inline size_t align16(size_t v) { return (v + 15) & ~(size_t)15; }

extern "C" void kernel_launch(void* const* d_in, const int* in_sizes, int n_in,
                              void* d_out, int out_size, void* d_ws, size_t ws_size,
                              hipStream_t stream)
{
    const float* x     = (const float*)d_in[0];
    const int*   ei    = (const int*)d_in[1];
    const float* W     = (const float*)d_in[2];
    const float* b     = (const float*)d_in[3];
    const float* gamma = (const float*)d_in[4];
    const float* beta  = (const float*)d_in[5];
    const float* geps  = (const float*)d_in[6];

    const int N = in_sizes[0] / D;
    const int E = in_sizes[1] / 2;
    const int* src = ei;        // edge_index[0,:]
    const int* dst = ei + E;    // edge_index[1,:]

    const int NB = (N + 1023) / 1024;   // scan chunks (40 for N=40000; <=256 ok)

    // ws layout (~3 MB): [stats 512f][cnt N] (zeroed) [rowptr N+1][cursor N][bsum NB][esrc E]
    char* ws = (char*)d_ws;
    size_t off = 0;
    float* stats  = (float*)(ws + off); off += 2048;
    int*   cnt    = (int*)  (ws + off); off += align16((size_t)N * 4);
    size_t zero_bytes = off;
    int*   rowptr = (int*)  (ws + off); off += align16((size_t)(N + 1) * 4);
    int*   cursor = (int*)  (ws + off); off += align16((size_t)N * 4);
    int*   bsum   = (int*)  (ws + off); off += align16((size_t)NB * 4);
    int*   esrc   = (int*)  (ws + off); off += align16((size_t)E * 4);

    hipMemsetAsync(stats, 0, zero_bytes, stream);

    if ((E & 3) == 0) {
        int E4 = E >> 2;
        count_kernel_vec<<<(E4 + 256) / 256, 256, 0, stream>>>(dst, cnt, E, N);
    } else {
        count_kernel<<<(E + 255) / 256, 256, 0, stream>>>(dst, cnt, E, N);
    }
    blocksum_kernel<<<NB, 256, 0, stream>>>(cnt, bsum, N);
    scanbsum_kernel<<<1, 256, 0, stream>>>(bsum, rowptr + N, NB);
    scanwrite_kernel<<<NB, 256, 0, stream>>>(cnt, bsum, rowptr, cursor, N);
    if ((E & 3) == 0) {
        int E4 = E >> 2;
        fill_kernel_vec<<<(E4 + 256) / 256, 256, 0, stream>>>(src, dst, cursor, esrc, E, N);
    } else {
        fill_kernel<<<(E + 255) / 256, 256, 0, stream>>>(src, dst, cursor, esrc, E, N);
    }

    // h -> d_out (fp32), then hlin in-place, then out in-place: all ordered.
    gather_kernel<<<(N + 7) / 8, 256, 0, stream>>>(
        (const float4*)x, rowptr, esrc, geps, (float4*)d_out, N, E);

    gemm_stats_kernel<<<(N + 63) / 64, 256, 0, stream>>>(
        (float*)d_out, W, b, stats, N);

    long ototal = (long)N * DH;
    out_kernel<<<(int)((ototal + 255) / 256), 256, 0, stream>>>(
        (const float2*)d_out, (const float2*)x, stats, gamma, beta,
        1.0f / (float)N, (float2*)d_out, ototal);
}

// Round 12
// 238.472 us; speedup vs baseline: 1.1605x; 1.1605x over previous
//
#include <hip/hip_runtime.h>

#define D 128
#define DH 64  // D/2 (float2 pairs)
#define KC 32  // GEMM k-chunk

// ---------------------------------------------------------------------------
// CSR build: count -> scanA/scanB -> fill (all bounds-checked, scalar atomics)
// ---------------------------------------------------------------------------
__global__ __launch_bounds__(256) void count_kernel(
    const int* __restrict__ dst, int* __restrict__ cnt, int E, int N)
{
    int e = blockIdx.x * 256 + threadIdx.x;
    if (e >= E) return;
    int d = dst[e];
    if ((unsigned)d < (unsigned)N) atomicAdd(&cnt[d], 1);
}

// scanA: per-chunk (1024 elems) local exclusive scan of cnt -> rowptr (no
// global offset yet); bsum[b] = chunk total. int4-coalesced.
__global__ __launch_bounds__(256) void scanA_kernel(
    const int* __restrict__ cnt, int* __restrict__ rowptr,
    int* __restrict__ bsum, int N)
{
    __shared__ int lds[256];
    const int t = threadIdx.x;
    const int k0 = blockIdx.x * 1024 + t * 4;
    int4 v = make_int4(0, 0, 0, 0);
    if (k0 + 3 < N) v = *(const int4*)(cnt + k0);
    else {
        if (k0 + 0 < N) v.x = cnt[k0 + 0];
        if (k0 + 1 < N) v.y = cnt[k0 + 1];
        if (k0 + 2 < N) v.z = cnt[k0 + 2];
        if (k0 + 3 < N) v.w = cnt[k0 + 3];
    }
    int s = v.x + v.y + v.z + v.w;
    lds[t] = s;
    __syncthreads();
    for (int off = 1; off < 256; off <<= 1) {
        int u = (t >= off) ? lds[t - off] : 0;
        __syncthreads();
        lds[t] += u;
        __syncthreads();
    }
    int excl = lds[t] - s;   // local exclusive prefix of this thread's quad
    int4 r;
    r.x = excl;
    r.y = excl + v.x;
    r.z = excl + v.x + v.y;
    r.w = excl + v.x + v.y + v.z;
    if (k0 + 3 < N) *(int4*)(rowptr + k0) = r;
    else {
        if (k0 + 0 < N) rowptr[k0 + 0] = r.x;
        if (k0 + 1 < N) rowptr[k0 + 1] = r.y;
        if (k0 + 2 < N) rowptr[k0 + 2] = r.z;
        if (k0 + 3 < N) rowptr[k0 + 3] = r.w;
    }
    if (t == 255) bsum[blockIdx.x] = lds[255];
}

// scanB: add global chunk offset, copy to cursor, write rowptr[N] = total.
__global__ __launch_bounds__(256) void scanB_kernel(
    const int* __restrict__ bsum, int* __restrict__ rowptr,
    int* __restrict__ cursor, int N, int NB)
{
    __shared__ int off_s, tot_s;
    if (threadIdx.x == 0) {
        int o = 0, tot = 0;
        for (int i = 0; i < NB; ++i) {
            if (i == (int)blockIdx.x) o = tot;
            tot += bsum[i];
        }
        off_s = o; tot_s = tot;
    }
    __syncthreads();
    const int offset = off_s;
    const int k0 = blockIdx.x * 1024 + threadIdx.x * 4;
    if (k0 + 3 < N) {
        int4 r = *(const int4*)(rowptr + k0);
        r.x += offset; r.y += offset; r.z += offset; r.w += offset;
        *(int4*)(rowptr + k0) = r;
        *(int4*)(cursor + k0) = r;
    } else {
        for (int k = k0; k < N && k < k0 + 4; ++k) {
            int r = rowptr[k] + offset;
            rowptr[k] = r; cursor[k] = r;
        }
    }
    if (blockIdx.x == 0 && threadIdx.x == 0) rowptr[N] = tot_s;
}

__global__ __launch_bounds__(256) void fill_kernel(
    const int* __restrict__ src, const int* __restrict__ dst,
    int* __restrict__ cursor, int* __restrict__ esrc, int E, int N)
{
    int e = blockIdx.x * 256 + threadIdx.x;
    if (e >= E) return;
    int d = dst[e];
    if ((unsigned)d >= (unsigned)N) return;
    int p = atomicAdd(&cursor[d], 1);
    if ((unsigned)p < (unsigned)E) esrc[p] = src[e];
}

// ---------------------------------------------------------------------------
// Gather (round-10 proven form): half-wave (32 lanes, float4) per node.
// h[i] = (1+eps)*x[i] + sum_{j in nbr(i)} x[j]; unrolled x4 for ILP.
// h written fp32 into d_out (overwritten later by hlin then out, in order).
// ---------------------------------------------------------------------------
__global__ __launch_bounds__(256) void gather_kernel(
    const float4* __restrict__ x4, const int* __restrict__ rowptr,
    const int* __restrict__ esrc, const float* __restrict__ geps,
    float4* __restrict__ h4, int N, int E)
{
    const float eps1 = 1.0f + geps[0];
    const int node = blockIdx.x * 8 + (threadIdx.x >> 5);
    const int lane = threadIdx.x & 31;       // 32 float4 slots per row
    if (node >= N) return;
    int s0 = rowptr[node];
    int s1 = rowptr[node + 1];
    s0 = max(0, min(s0, E));       // any CSR bug stays finite
    s1 = max(s0, min(s1, E));
    float4 a = x4[(long)node * 32 + lane];
    a.x *= eps1; a.y *= eps1; a.z *= eps1; a.w *= eps1;
    int e = s0;
    for (; e + 3 < s1; e += 4) {
        int j0 = esrc[e], j1 = esrc[e + 1], j2 = esrc[e + 2], j3 = esrc[e + 3];
        if ((unsigned)j0 < (unsigned)N) { float4 v = x4[(long)j0 * 32 + lane]; a.x += v.x; a.y += v.y; a.z += v.z; a.w += v.w; }
        if ((unsigned)j1 < (unsigned)N) { float4 v = x4[(long)j1 * 32 + lane]; a.x += v.x; a.y += v.y; a.z += v.z; a.w += v.w; }
        if ((unsigned)j2 < (unsigned)N) { float4 v = x4[(long)j2 * 32 + lane]; a.x += v.x; a.y += v.y; a.z += v.z; a.w += v.w; }
        if ((unsigned)j3 < (unsigned)N) { float4 v = x4[(long)j3 * 32 + lane]; a.x += v.x; a.y += v.y; a.z += v.z; a.w += v.w; }
    }
    for (; e < s1; ++e) {
        int j = esrc[e];
        if ((unsigned)j < (unsigned)N) { float4 v = x4[(long)j * 32 + lane]; a.x += v.x; a.y += v.y; a.z += v.z; a.w += v.w; }
    }
    h4[(long)node * 32 + lane] = a;
}

// ---------------------------------------------------------------------------
// Register-tiled GEMM + BN stats (round-10 proven): hlin = h @ W^T + b,
// col sum/sumsq. Block = 16x16; tile 64x128; c[4][8] per thread.
// hb read AND written in-place (d_out); rows block-private.
// ---------------------------------------------------------------------------
__global__ __launch_bounds__(256) void gemm_stats_kernel(
    float* hb, const float* __restrict__ W,
    const float* __restrict__ bb, float* __restrict__ stats, int N)
{
    __shared__ __align__(16) float At[KC][68];
    __shared__ __align__(16) float Bs[KC][132];
    __shared__ float red[16][128];

    const int tid = threadIdx.x;
    const int tx = tid & 15;
    const int ty = tid >> 4;
    const int row0 = blockIdx.x * 64;

    float c[4][8];
    #pragma unroll
    for (int r = 0; r < 4; ++r)
        #pragma unroll
        for (int cc = 0; cc < 8; ++cc) c[r][cc] = 0.0f;

    for (int k0 = 0; k0 < D; k0 += KC) {
        #pragma unroll
        for (int q = 0; q < 2; ++q) {
            int s = q * 256 + tid;
            int r = s >> 3;
            int kq = s & 7;
            int grow = row0 + r;
            float4 v = make_float4(0.f, 0.f, 0.f, 0.f);
            if (grow < N) v = *(const float4*)(hb + (long)grow * D + k0 + kq * 4);
            At[kq * 4 + 0][r] = v.x; At[kq * 4 + 1][r] = v.y;
            At[kq * 4 + 2][r] = v.z; At[kq * 4 + 3][r] = v.w;
        }
        #pragma unroll
        for (int q = 0; q < 4; ++q) {
            int s = q * 256 + tid;
            int col = s >> 3;
            int kq = s & 7;
            float4 v = *(const float4*)(W + (long)col * D + k0 + kq * 4);
            Bs[kq * 4 + 0][col] = v.x; Bs[kq * 4 + 1][col] = v.y;
            Bs[kq * 4 + 2][col] = v.z; Bs[kq * 4 + 3][col] = v.w;
        }
        __syncthreads();
        #pragma unroll
        for (int k = 0; k < KC; ++k) {
            float4 av = *(const float4*)&At[k][ty * 4];
            float4 b0 = *(const float4*)&Bs[k][tx * 8];
            float4 b1 = *(const float4*)&Bs[k][tx * 8 + 4];
            float a[4] = {av.x, av.y, av.z, av.w};
            float b[8] = {b0.x, b0.y, b0.z, b0.w, b1.x, b1.y, b1.z, b1.w};
            #pragma unroll
            for (int r = 0; r < 4; ++r)
                #pragma unroll
                for (int cc = 0; cc < 8; ++cc)
                    c[r][cc] = fmaf(a[r], b[cc], c[r][cc]);
        }
        __syncthreads();
    }

    float bias[8];
    #pragma unroll
    for (int cc = 0; cc < 8; ++cc) bias[cc] = bb[tx * 8 + cc];

    float psum[8], psq[8];
    #pragma unroll
    for (int cc = 0; cc < 8; ++cc) { psum[cc] = 0.f; psq[cc] = 0.f; }

    #pragma unroll
    for (int r = 0; r < 4; ++r) {
        int grow = row0 + ty * 4 + r;
        if (grow < N) {
            float v[8];
            #pragma unroll
            for (int cc = 0; cc < 8; ++cc) {
                v[cc] = c[r][cc] + bias[cc];
                psum[cc] += v[cc];
                psq[cc]  = fmaf(v[cc], v[cc], psq[cc]);
            }
            float4* dst0 = (float4*)(hb + (long)grow * D + tx * 8);
            dst0[0] = make_float4(v[0], v[1], v[2], v[3]);
            dst0[1] = make_float4(v[4], v[5], v[6], v[7]);
        }
    }

    #pragma unroll
    for (int cc = 0; cc < 8; ++cc) red[ty][tx * 8 + cc] = psum[cc];
    __syncthreads();
    if (tid < 128) {
        float s = 0.f;
        #pragma unroll
        for (int t = 0; t < 16; ++t) s += red[t][tid];
        unsafeAtomicAdd(&stats[tid], s);
    }
    __syncthreads();
    #pragma unroll
    for (int cc = 0; cc < 8; ++cc) red[ty][tx * 8 + cc] = psq[cc];
    __syncthreads();
    if (tid < 128) {
        float s = 0.f;
        #pragma unroll
        for (int t = 0; t < 16; ++t) s += red[t][tid];
        unsafeAtomicAdd(&stats[128 + tid], s);
    }
}

// ---------------------------------------------------------------------------
// Epilogue (finalize fused): each block derives ginv/shift from raw stats,
// then out = relu(hlin*ginv + shift) + x. Same-index float2 alias
// (read pair t, write pair t) -> race-free. NO __restrict__ on the alias.
// ---------------------------------------------------------------------------
__global__ __launch_bounds__(256) void out_kernel(
    const float2* hlin2, const float2* __restrict__ x2,
    const float* __restrict__ stats, const float* __restrict__ gamma,
    const float* __restrict__ beta, float invN, float2* dout, long total)
{
    __shared__ float ginv[D], sh[D];
    if (threadIdx.x < D) {
        int j = threadIdx.x;
        float mean = stats[j] * invN;
        float var  = stats[128 + j] * invN - mean * mean;
        float gv   = gamma[j] * rsqrtf(var + 1e-5f);
        ginv[j] = gv;
        sh[j]   = beta[j] - mean * gv;
    }
    __syncthreads();
    long t = (long)blockIdx.x * 256 + threadIdx.x;
    if (t >= total) return;
    int f = (int)(t & 63);
    float2 hv = hlin2[t];
    float2 xv = x2[t];
    float v0 = fmaf(hv.x, ginv[2 * f],     sh[2 * f]);
    float v1 = fmaf(hv.y, ginv[2 * f + 1], sh[2 * f + 1]);
    v0 = fmaxf(v0, 0.0f) + xv.x;
    v1 = fmaxf(v1, 0.0f) + xv.y;
    dout[t] = make_float2(v0, v1);
}

// ---------------------------------------------------------------------------
static inline size_t align16(size_t v) { return (v + 15) & ~(size_t)15; }

extern "C" void kernel_launch(void* const* d_in, const int* in_sizes, int n_in,
                              void* d_out, int out_size, void* d_ws, size_t ws_size,
                              hipStream_t stream)
{
    const float* x     = (const float*)d_in[0];
    const int*   ei    = (const int*)d_in[1];
    const float* W     = (const float*)d_in[2];
    const float* b     = (const float*)d_in[3];
    const float* gamma = (const float*)d_in[4];
    const float* beta  = (const float*)d_in[5];
    const float* geps  = (const float*)d_in[6];

    const int N = in_sizes[0] / D;
    const int E = in_sizes[1] / 2;
    const int* src = ei;        // edge_index[0,:]
    const int* dst = ei + E;    // edge_index[1,:]

    const int NB = (N + 1023) / 1024;   // scan chunks (40 for N=40000)

    // ws layout (~3 MB): [stats 512f][cnt N] (zeroed) [rowptr N+1][cursor N][bsum NB][esrc E]
    char* ws = (char*)d_ws;
    size_t off = 0;
    float* stats  = (float*)(ws + off); off += 2048;
    int*   cnt    = (int*)  (ws + off); off += align16((size_t)N * 4);
    size_t zero_bytes = off;
    int*   rowptr = (int*)  (ws + off); off += align16((size_t)(N + 1) * 4);
    int*   cursor = (int*)  (ws + off); off += align16((size_t)N * 4);
    int*   bsum   = (int*)  (ws + off); off += align16((size_t)NB * 4);
    int*   esrc   = (int*)  (ws + off); off += align16((size_t)E * 4);

    hipMemsetAsync(stats, 0, zero_bytes, stream);

    count_kernel<<<(E + 255) / 256, 256, 0, stream>>>(dst, cnt, E, N);
    scanA_kernel<<<NB, 256, 0, stream>>>(cnt, rowptr, bsum, N);
    scanB_kernel<<<NB, 256, 0, stream>>>(bsum, rowptr, cursor, N, NB);
    fill_kernel<<<(E + 255) / 256, 256, 0, stream>>>(src, dst, cursor, esrc, E, N);

    // h -> d_out (fp32), then hlin in-place, then out in-place: all ordered.
    gather_kernel<<<(N + 7) / 8, 256, 0, stream>>>(
        (const float4*)x, rowptr, esrc, geps, (float4*)d_out, N, E);

    gemm_stats_kernel<<<(N + 63) / 64, 256, 0, stream>>>(
        (float*)d_out, W, b, stats, N);

    long ototal = (long)N * DH;
    out_kernel<<<(int)((ototal + 255) / 256), 256, 0, stream>>>(
        (const float2*)d_out, (const float2*)x, stats, gamma, beta,
        1.0f / (float)N, (float2*)d_out, ototal);
}